// Round 1
// baseline (1374.578 us; speedup 1.0000x reference)
//
#include <hip/hip_runtime.h>
#include <cstddef>
#include <math.h>

// VQ layer: x[131072,128] fp32, codebook[1024,128] fp32.
// Outputs (flat in d_out, fp32): z_st[16777216], q_loss, c_loss, perplexity.
//
// Numerics: argmin over k of c_norm_k - 2*dot(x_i, c_k)  (x_norm and the
// max(.,0) clamp provably don't affect the argmin: dist ≈ x_norm ≥ ~60 > 0).
// fp32 pass with rigorous worst-case error margin; near-tie rows refined in
// fp64 so the argmin matches an fp64-exact reference on every row.

#define NROWS 131072
#define KC 1024
#define DD 128

struct WS {
  unsigned wl_count;     // refine-worklist size
  unsigned pad0;
  double lossSum;        // sum of (z-x)^2 over all elements
  unsigned counts[KC];   // assignment histogram
  float cnorm32[KC];
  double cnorm64[KC];
  unsigned wl[NROWS];    // refine worklist (row ids)
};
// memset-to-zero region: [0, offsetof(WS,cnorm32)) = wl_count+lossSum+counts.
// total WS footprint ≈ 541 KB — assumed < ws_size.

__global__ __launch_bounds__(256) void k_cnorm(const float* __restrict__ cb,
                                               WS* __restrict__ ws) {
  int k = blockIdx.x * 256 + threadIdx.x;
  const float* cr = cb + (size_t)k * DD;
  double s = 0.0;
  for (int j = 0; j < DD; ++j) { double v = (double)cr[j]; s = fma(v, v, s); }
  ws->cnorm64[k] = s;
  ws->cnorm32[k] = (float)s;
}

// One thread per row. x row lives in 128 VGPRs; codebook addresses are
// wave-uniform (k is the loop counter) -> scalar loads feeding v_fmac v,s,v.
// 4 accumulators break the dependent-FMA chain (4cyc latency / 2cyc issue).
//
// Worst-case fp32 key error: |partial dot| <= ||x||*||c|| <= 14.4*0.011 < 0.25
// -> per-op rounding <= 2^-27; 128 ops + combine -> key err <= ~2e-6,
// top-2 diff err <= 4e-6. MARGIN = 8e-6 is worst-case safe; flags ~0.25% of
// rows to the fp64 refine pass.
__global__ __launch_bounds__(256, 2) void k_assign(
    const float* __restrict__ x, const float* __restrict__ cb,
    float* __restrict__ out, WS* __restrict__ ws) {
  __shared__ unsigned hist[KC];
  for (int i = threadIdx.x; i < KC; i += 256) hist[i] = 0;
  __syncthreads();

  int row = blockIdx.x * 256 + threadIdx.x;
  const float* xr = x + (size_t)row * DD;
  float xv[DD];
#pragma unroll
  for (int j = 0; j < DD; j += 4) {
    float4 t = *(const float4*)(xr + j);
    xv[j] = t.x; xv[j + 1] = t.y; xv[j + 2] = t.z; xv[j + 3] = t.w;
  }

  float best = 3.4e38f, best2 = 3.4e38f;
  int bi = 0;
  for (int k = 0; k < KC; ++k) {
    const float* cr = cb + (size_t)k * DD;
    float a0 = 0.f, a1 = 0.f, a2 = 0.f, a3 = 0.f;
#pragma unroll
    for (int j = 0; j < DD; j += 4) {
      a0 = fmaf(xv[j],     cr[j],     a0);
      a1 = fmaf(xv[j + 1], cr[j + 1], a1);
      a2 = fmaf(xv[j + 2], cr[j + 2], a2);
      a3 = fmaf(xv[j + 3], cr[j + 3], a3);
    }
    float key = fmaf(-2.0f, (a0 + a1) + (a2 + a3), ws->cnorm32[k]);
    if (key < best) { best2 = best; best = key; bi = k; }   // strict < : first-index tie-break
    else if (key < best2) { best2 = key; }
  }

  const float MARGIN = 8e-6f;
  bool flagged = (best2 - best) < MARGIN;
  float s = 0.0f;
  if (flagged) {
    unsigned slot = atomicAdd(&ws->wl_count, 1u);
    ws->wl[slot] = (unsigned)row;
  } else {
    atomicAdd(&hist[bi], 1u);
    const float* cr = cb + (size_t)bi * DD;
    float* orow = out + (size_t)row * DD;
#pragma unroll
    for (int j = 0; j < DD; j += 4) {
      float4 c4 = *(const float4*)(cr + j);
      float d0 = c4.x - xv[j];
      float d1 = c4.y - xv[j + 1];
      float d2 = c4.z - xv[j + 2];
      float d3 = c4.w - xv[j + 3];
      float4 o4;                      // z_st = x + (z - x), same rounding as ref
      o4.x = xv[j] + d0; o4.y = xv[j + 1] + d1;
      o4.z = xv[j + 2] + d2; o4.w = xv[j + 3] + d3;
      *(float4*)(orow + j) = o4;
      s = fmaf(d0, d0, s); s = fmaf(d1, d1, s);
      s = fmaf(d2, d2, s); s = fmaf(d3, d3, s);
    }
  }
  // wave-reduce loss partials (flagged threads contribute 0)
  for (int off = 32; off; off >>= 1) s += __shfl_down(s, off);
  if ((threadIdx.x & 63) == 0) atomicAdd(&ws->lossSum, (double)s);

  __syncthreads();
  for (int i = threadIdx.x; i < KC; i += 256) {
    unsigned h = hist[i];
    if (h) atomicAdd(&ws->counts[i], h);
  }
}

// One wave per flagged row; lane L scans codes [16L, 16L+16) in fp64,
// butterfly-argmin across lanes (value, then smallest index).
__global__ __launch_bounds__(256) void k_refine(
    const float* __restrict__ x, const float* __restrict__ cb,
    float* __restrict__ out, WS* __restrict__ ws) {
  unsigned count = ws->wl_count;
  int gwave = (blockIdx.x * 256 + (int)threadIdx.x) >> 6;
  int lane = threadIdx.x & 63;
  int nwaves = gridDim.x * 4;
  for (unsigned w = gwave; w < count; w += nwaves) {
    int row = (int)ws->wl[w];
    const float* xr = x + (size_t)row * DD;
    double bkey = 1e300;
    int bidx = 0;
    for (int m = 0; m < 16; ++m) {
      int k = lane * 16 + m;
      const float* cr = cb + (size_t)k * DD;
      double acc = 0.0;
      for (int j = 0; j < DD; ++j)
        acc = fma((double)xr[j], (double)cr[j], acc);
      double key = fma(-2.0, acc, ws->cnorm64[k]);
      if (key < bkey) { bkey = key; bidx = k; }  // ascending k keeps first min
    }
    for (int off = 32; off; off >>= 1) {
      double ok = __shfl_xor(bkey, off);
      int oi = __shfl_xor(bidx, off);
      if (ok < bkey || (ok == bkey && oi < bidx)) { bkey = ok; bidx = oi; }
    }
    if (lane == 0) atomicAdd(&ws->counts[bidx], 1u);
    const float* cr = cb + (size_t)bidx * DD;
    float s = 0.0f;
#pragma unroll
    for (int t = 0; t < 2; ++t) {
      int j = lane * 2 + t;
      float xvj = xr[j];
      float d = cr[j] - xvj;
      out[(size_t)row * DD + j] = xvj + d;
      s = fmaf(d, d, s);
    }
    for (int off = 32; off; off >>= 1) s += __shfl_down(s, off);
    if (lane == 0) atomicAdd(&ws->lossSum, (double)s);
  }
}

__global__ __launch_bounds__(256) void k_final(float* __restrict__ out,
                                               WS* __restrict__ ws) {
  __shared__ double hs[256];
  double h = 0.0;
  for (int i = threadIdx.x; i < KC; i += 256) {
    double p = (double)ws->counts[i] / (double)NROWS;
    h += p * log(p + 1e-10);
  }
  hs[threadIdx.x] = h;
  __syncthreads();
  for (int off = 128; off; off >>= 1) {
    if ((int)threadIdx.x < off) hs[threadIdx.x] += hs[threadIdx.x + off];
    __syncthreads();
  }
  if (threadIdx.x == 0) {
    double loss = ws->lossSum / (double)((size_t)NROWS * DD);
    out[16777216] = (float)loss;       // quantization_loss
    out[16777217] = (float)loss;       // commitment_loss (same value)
    out[16777218] = (float)exp(-hs[0]);// perplexity
  }
}

extern "C" void kernel_launch(void* const* d_in, const int* in_sizes, int n_in,
                              void* d_out, int out_size, void* d_ws, size_t ws_size,
                              hipStream_t stream) {
  const float* x = (const float*)d_in[0];
  const float* cb = (const float*)d_in[1];
  float* out = (float*)d_out;
  WS* ws = (WS*)d_ws;

  hipMemsetAsync(d_ws, 0, offsetof(WS, cnorm32), stream);
  k_cnorm<<<KC / 256, 256, 0, stream>>>(cb, ws);
  k_assign<<<NROWS / 256, 256, 0, stream>>>(x, cb, out, ws);
  k_refine<<<128, 256, 0, stream>>>(x, cb, out, ws);
  k_final<<<1, 256, 0, stream>>>(out, ws);
}

// Round 2
// 1269.615 us; speedup vs baseline: 1.0827x; 1.0827x over previous
//
#include <hip/hip_runtime.h>
#include <cstddef>
#include <math.h>

// VQ layer via bf16-split MFMA GEMM.
// S = X·C^T as 3 bf16 MFMA passes (hi*hi + hi*lo + lo*hi); argmin key
// = cnorm - 2*dot computed as argmax of acc where acc0 = -0.5*cnorm.
// Near-ties (< 1.5e-5 in key space) refined in fp64.

#define NROWS 131072
#define KC 1024
#define DD 128
#define LDK 136   // 128 + 8 ushort pad -> 272B row stride, conflict-free frags

typedef __attribute__((ext_vector_type(8))) short short8;
typedef __attribute__((ext_vector_type(4))) float f32x4;

struct WS {
  unsigned wl_count;           // zeroed
  unsigned pad0;               // zeroed
  double lossSum;              // zeroed
  unsigned counts[KC];         // zeroed
  float cnorm32[KC];
  double cnorm64[KC];
  unsigned rowidx[NROWS];
  unsigned wl[NROWS];
  unsigned short chi[KC * DD]; // codebook bf16 hi
  unsigned short clo[KC * DD]; // codebook bf16 lo
};

static __device__ __forceinline__ unsigned short f2bf_rn(float f) {
  unsigned u = __float_as_uint(f);
  unsigned r = (u + 0x7FFFu + ((u >> 16) & 1u)) >> 16;  // RN-even
  return (unsigned short)r;
}
static __device__ __forceinline__ float bf2f(unsigned short h) {
  return __uint_as_float(((unsigned)h) << 16);
}

__global__ __launch_bounds__(256) void k_cvt(const float* __restrict__ cb,
                                             WS* __restrict__ ws) {
  int gid = blockIdx.x * 256 + threadIdx.x;     // 32768 threads, 4 elems each
  int e0 = gid * 4;
  float4 c4 = *(const float4*)(cb + e0);
  float cf[4] = {c4.x, c4.y, c4.z, c4.w};
#pragma unroll
  for (int j = 0; j < 4; ++j) {
    unsigned short h = f2bf_rn(cf[j]);
    float lo = cf[j] - bf2f(h);
    ws->chi[e0 + j] = h;
    ws->clo[e0 + j] = f2bf_rn(lo);
  }
}

__global__ __launch_bounds__(256) void k_cnorm(const float* __restrict__ cb,
                                               WS* __restrict__ ws) {
  int k = blockIdx.x * 256 + threadIdx.x;
  const float* cr = cb + (size_t)k * DD;
  double s = 0.0;
  for (int j = 0; j < DD; ++j) { double v = (double)cr[j]; s = fma(v, v, s); }
  ws->cnorm64[k] = s;
  ws->cnorm32[k] = (float)s;
}

// block = 256 thr = 4 waves; each wave owns 64 rows (B-frags resident in
// regs, hi+lo, K=128); codes stream through LDS in chunks of 128.
__global__ __launch_bounds__(256, 2) void k_assign(
    const float* __restrict__ x, WS* __restrict__ ws) {
  __shared__ unsigned short ldsA[2][128][LDK];  // [hi/lo][code][k]
  __shared__ float cns[128];

  const int tid = threadIdx.x;
  const int wave = tid >> 6, lane = tid & 63;
  const int l15 = lane & 15, quad = lane >> 4;
  const int rowbase = blockIdx.x * 256 + wave * 64;

  // ---- load resident B-fragments (this wave's 64 rows, bf16 hi/lo) ----
  short8 Bhi[4][4], Blo[4][4];
#pragma unroll
  for (int Nf = 0; Nf < 4; ++Nf) {
    const float* xr = x + (size_t)(rowbase + Nf * 16 + l15) * DD;
#pragma unroll
    for (int ks = 0; ks < 4; ++ks) {
      int k0 = ks * 32 + quad * 8;
      float4 u = *(const float4*)(xr + k0);
      float4 v = *(const float4*)(xr + k0 + 4);
      float f[8] = {u.x, u.y, u.z, u.w, v.x, v.y, v.z, v.w};
      short8 bh, bl;
#pragma unroll
      for (int j = 0; j < 8; ++j) {
        unsigned short h = f2bf_rn(f[j]);
        bh[j] = (short)h;
        bl[j] = (short)f2bf_rn(f[j] - bf2f(h));
      }
      Bhi[Nf][ks] = bh; Blo[Nf][ks] = bl;
    }
  }

  // running top-2 (maximize acc), per Nf
  float rv1[4], rv2[4];
  int ri1[4], ri2[4];
#pragma unroll
  for (int Nf = 0; Nf < 4; ++Nf) { rv1[Nf] = -3.4e38f; rv2[Nf] = -3.4e38f; ri1[Nf] = 0; ri2[Nf] = 0; }

  for (int cc = 0; cc < 8; ++cc) {            // 8 chunks of 128 codes
    __syncthreads();
    // ---- stage chunk: 128 codes hi+lo -> LDS (padded), + cnorms ----
#pragma unroll
    for (int it = 0; it < 8; ++it) {
      int s = it * 256 + tid;                 // 2048 16B-segments per variant
      int row = s >> 4, seg = s & 15;
      const short8* gh = (const short8*)&ws->chi[((size_t)(cc * 128 + row)) * DD + seg * 8];
      const short8* gl = (const short8*)&ws->clo[((size_t)(cc * 128 + row)) * DD + seg * 8];
      *(short8*)&ldsA[0][row][seg * 8] = *gh;
      *(short8*)&ldsA[1][row][seg * 8] = *gl;
    }
    if (tid < 128) cns[tid] = ws->cnorm32[cc * 128 + tid];
    __syncthreads();

#pragma unroll
    for (int half = 0; half < 2; ++half) {    // 64 codes per half
      f32x4 acc[4][4];
#pragma unroll
      for (int Mf = 0; Mf < 4; ++Mf) {
        f32x4 cn4 = *(const f32x4*)&cns[half * 64 + Mf * 16 + quad * 4];
        f32x4 ini = -0.5f * cn4;
#pragma unroll
        for (int Nf = 0; Nf < 4; ++Nf) acc[Mf][Nf] = ini;
      }
#pragma unroll
      for (int ks = 0; ks < 4; ++ks) {
        short8 Ah[4], Al[4];
#pragma unroll
        for (int Mf = 0; Mf < 4; ++Mf)
          Ah[Mf] = *(const short8*)&ldsA[0][half * 64 + Mf * 16 + l15][ks * 32 + quad * 8];
#pragma unroll
        for (int Mf = 0; Mf < 4; ++Mf)
          Al[Mf] = *(const short8*)&ldsA[1][half * 64 + Mf * 16 + l15][ks * 32 + quad * 8];
#pragma unroll
        for (int Mf = 0; Mf < 4; ++Mf)
#pragma unroll
          for (int Nf = 0; Nf < 4; ++Nf)
            acc[Mf][Nf] = __builtin_amdgcn_mfma_f32_16x16x32_bf16(Ah[Mf], Bhi[Nf][ks], acc[Mf][Nf], 0, 0, 0);
#pragma unroll
        for (int Mf = 0; Mf < 4; ++Mf)
#pragma unroll
          for (int Nf = 0; Nf < 4; ++Nf)
            acc[Mf][Nf] = __builtin_amdgcn_mfma_f32_16x16x32_bf16(Ah[Mf], Blo[Nf][ks], acc[Mf][Nf], 0, 0, 0);
#pragma unroll
        for (int Mf = 0; Mf < 4; ++Mf)
#pragma unroll
          for (int Nf = 0; Nf < 4; ++Nf)
            acc[Mf][Nf] = __builtin_amdgcn_mfma_f32_16x16x32_bf16(Al[Mf], Bhi[Nf][ks], acc[Mf][Nf], 0, 0, 0);
      }
      // ---- top-2 epilogue: in-lane over 16, butterfly over quads ----
      int cb0 = cc * 128 + half * 64 + quad * 4;
#pragma unroll
      for (int Nf = 0; Nf < 4; ++Nf) {
        float v1 = -3.4e38f, v2 = -3.4e38f; int i1 = 0, i2 = 0;
#pragma unroll
        for (int Mf = 0; Mf < 4; ++Mf)
#pragma unroll
          for (int r = 0; r < 4; ++r) {
            float v = acc[Mf][Nf][r];
            int idx = cb0 + Mf * 16 + r;
            if (v > v1 || (v == v1 && idx < i1)) { v2 = v1; i2 = i1; v1 = v; i1 = idx; }
            else if (v > v2 || (v == v2 && idx < i2)) { v2 = v; i2 = idx; }
          }
#pragma unroll
        for (int st = 16; st <= 32; st <<= 1) {
          float ov1 = __shfl_xor(v1, st), ov2 = __shfl_xor(v2, st);
          int oi1 = __shfl_xor(i1, st), oi2 = __shfl_xor(i2, st);
          if (ov1 > v1 || (ov1 == v1 && oi1 < i1)) { v2 = v1; i2 = i1; v1 = ov1; i1 = oi1; }
          else if (ov1 > v2 || (ov1 == v2 && oi1 < i2)) { v2 = ov1; i2 = oi1; }
          if (ov2 > v2 || (ov2 == v2 && oi2 < i2)) { v2 = ov2; i2 = oi2; }
        }
        if (v1 > rv1[Nf] || (v1 == rv1[Nf] && i1 < ri1[Nf])) {
          if (rv1[Nf] > v2 || (rv1[Nf] == v2 && ri1[Nf] < i2)) { v2 = rv1[Nf]; i2 = ri1[Nf]; }
          rv2[Nf] = v2; ri2[Nf] = i2; rv1[Nf] = v1; ri1[Nf] = i1;
        } else {
          if (v1 > rv2[Nf] || (v1 == rv2[Nf] && i1 < ri2[Nf])) { rv2[Nf] = v1; ri2[Nf] = i1; }
        }
      }
    }
  }

  // key = -2*acc; key gap = 2*acc gap. Flag if acc gap < 7.5e-6.
  const float ACC_MARGIN = 7.5e-6f;
#pragma unroll
  for (int Nf = 0; Nf < 4; ++Nf) {
    if (quad == 0) {
      int row = rowbase + Nf * 16 + l15;
      if ((rv1[Nf] - rv2[Nf]) < ACC_MARGIN) {
        unsigned slot = atomicAdd(&ws->wl_count, 1u);
        ws->wl[slot] = (unsigned)row;
      } else {
        ws->rowidx[row] = (unsigned)ri1[Nf];
        atomicAdd(&ws->counts[ri1[Nf]], 1u);
      }
    }
  }
}

// fp64 exact argmin for flagged rows; one wave per row.
__global__ __launch_bounds__(256) void k_refine(
    const float* __restrict__ x, const float* __restrict__ cb,
    WS* __restrict__ ws) {
  unsigned count = ws->wl_count;
  int gwave = (blockIdx.x * 256 + (int)threadIdx.x) >> 6;
  int lane = threadIdx.x & 63;
  int nwaves = gridDim.x * 4;
  for (unsigned w = gwave; w < count; w += nwaves) {
    int row = (int)ws->wl[w];
    const float* xr = x + (size_t)row * DD;
    double bkey = 1e300; int bidx = 0;
    for (int m = 0; m < 16; ++m) {
      int k = lane * 16 + m;
      const float* cr = cb + (size_t)k * DD;
      double acc = 0.0;
      for (int j = 0; j < DD; ++j)
        acc = fma((double)xr[j], (double)cr[j], acc);
      double key = fma(-2.0, acc, ws->cnorm64[k]);
      if (key < bkey) { bkey = key; bidx = k; }
    }
    for (int off = 32; off; off >>= 1) {
      double ok = __shfl_xor(bkey, off);
      int oi = __shfl_xor(bidx, off);
      if (ok < bkey || (ok == bkey && oi < bidx)) { bkey = ok; bidx = oi; }
    }
    if (lane == 0) {
      ws->rowidx[row] = (unsigned)bidx;
      atomicAdd(&ws->counts[bidx], 1u);
    }
  }
}

// z_st + loss for all rows: thread per float4.
__global__ __launch_bounds__(256) void k_gather(
    const float* __restrict__ x, const float* __restrict__ cb,
    float* __restrict__ out, WS* __restrict__ ws) {
  int gid = blockIdx.x * 256 + threadIdx.x;   // 4194304 threads
  int row = gid >> 5, seg = gid & 31;
  unsigned idx = ws->rowidx[row];
  float4 c4 = *(const float4*)(cb + (size_t)idx * DD + seg * 4);
  float4 x4 = *(const float4*)(x + (size_t)row * DD + seg * 4);
  float d0 = c4.x - x4.x, d1 = c4.y - x4.y, d2 = c4.z - x4.z, d3 = c4.w - x4.w;
  float4 o4;
  o4.x = x4.x + d0; o4.y = x4.y + d1; o4.z = x4.z + d2; o4.w = x4.w + d3;
  *(float4*)(out + (size_t)row * DD + seg * 4) = o4;
  float s = fmaf(d0, d0, fmaf(d1, d1, fmaf(d2, d2, d3 * d3)));
  for (int off = 32; off; off >>= 1) s += __shfl_down(s, off);
  if ((threadIdx.x & 63) == 0) atomicAdd(&ws->lossSum, (double)s);
}

__global__ __launch_bounds__(256) void k_final(float* __restrict__ out,
                                               WS* __restrict__ ws) {
  __shared__ double hs[256];
  double h = 0.0;
  for (int i = threadIdx.x; i < KC; i += 256) {
    double p = (double)ws->counts[i] / (double)NROWS;
    h += p * log(p + 1e-10);
  }
  hs[threadIdx.x] = h;
  __syncthreads();
  for (int off = 128; off; off >>= 1) {
    if ((int)threadIdx.x < off) hs[threadIdx.x] += hs[threadIdx.x + off];
    __syncthreads();
  }
  if (threadIdx.x == 0) {
    double loss = ws->lossSum / (double)((size_t)NROWS * DD);
    out[16777216] = (float)loss;
    out[16777217] = (float)loss;
    out[16777218] = (float)exp(-hs[0]);
  }
}

extern "C" void kernel_launch(void* const* d_in, const int* in_sizes, int n_in,
                              void* d_out, int out_size, void* d_ws, size_t ws_size,
                              hipStream_t stream) {
  const float* x = (const float*)d_in[0];
  const float* cb = (const float*)d_in[1];
  float* out = (float*)d_out;
  WS* ws = (WS*)d_ws;

  hipMemsetAsync(d_ws, 0, offsetof(WS, cnorm32), stream);
  k_cvt<<<128, 256, 0, stream>>>(cb, ws);
  k_cnorm<<<KC / 256, 256, 0, stream>>>(cb, ws);
  k_assign<<<NROWS / 256, 256, 0, stream>>>(x, ws);
  k_refine<<<128, 256, 0, stream>>>(x, cb, ws);
  k_gather<<<NROWS * 32 / 256, 256, 0, stream>>>(x, cb, out, ws);
  k_final<<<1, 256, 0, stream>>>(out, ws);
}

// Round 3
// 473.606 us; speedup vs baseline: 2.9024x; 2.6807x over previous
//
#include <hip/hip_runtime.h>
#include <cstddef>
#include <math.h>

// VQ layer via bf16-split MFMA GEMM.
// S = X·C^T as 3 bf16 MFMA passes (hi*hi + hi*lo + lo*hi); argmin key
// = cnorm - 2*dot computed as argmax of acc where acc0 = -0.5*cnorm.
// Near-ties (< 1.5e-5 in key space) refined in fp64.

#define NROWS 131072
#define KC 1024
#define DD 128
#define LDK 136   // 128 + 8 ushort pad -> 272B row stride, conflict-free frags
#define GATHER_BLOCKS 4096

typedef __attribute__((ext_vector_type(8))) short short8;
typedef __attribute__((ext_vector_type(4))) float f32x4;

struct WS {
  unsigned wl_count;           // zeroed
  unsigned pad0;               // zeroed
  double lossSum;              // (unused, layout padding)
  unsigned counts[KC];         // zeroed
  float cnorm32[KC];
  double cnorm64[KC];
  double lossPart[GATHER_BLOCKS];
  unsigned rowidx[NROWS];
  unsigned wl[NROWS];
  unsigned short chi[KC * DD]; // codebook bf16 hi
  unsigned short clo[KC * DD]; // codebook bf16 lo
};

static __device__ __forceinline__ unsigned short f2bf_rn(float f) {
  unsigned u = __float_as_uint(f);
  unsigned r = (u + 0x7FFFu + ((u >> 16) & 1u)) >> 16;  // RN-even
  return (unsigned short)r;
}
static __device__ __forceinline__ float bf2f(unsigned short h) {
  return __uint_as_float(((unsigned)h) << 16);
}

__global__ __launch_bounds__(256) void k_cvt(const float* __restrict__ cb,
                                             WS* __restrict__ ws) {
  int gid = blockIdx.x * 256 + threadIdx.x;     // 32768 threads, 4 elems each
  int e0 = gid * 4;
  float4 c4 = *(const float4*)(cb + e0);
  float cf[4] = {c4.x, c4.y, c4.z, c4.w};
#pragma unroll
  for (int j = 0; j < 4; ++j) {
    unsigned short h = f2bf_rn(cf[j]);
    float lo = cf[j] - bf2f(h);
    ws->chi[e0 + j] = h;
    ws->clo[e0 + j] = f2bf_rn(lo);
  }
}

__global__ __launch_bounds__(256) void k_cnorm(const float* __restrict__ cb,
                                               WS* __restrict__ ws) {
  int k = blockIdx.x * 256 + threadIdx.x;
  const float* cr = cb + (size_t)k * DD;
  double s = 0.0;
  for (int j = 0; j < DD; ++j) { double v = (double)cr[j]; s = fma(v, v, s); }
  ws->cnorm64[k] = s;
  ws->cnorm32[k] = (float)s;
}

// block = 256 thr = 4 waves; each wave owns 32 rows (B-frags resident in
// regs, hi+lo, K=128, 64 VGPRs); codes stream through LDS in chunks of 128.
// Register budget: Bfrags 64 + acc 32 + A-frags 32 + top2 8 + addr ~30
// => ~170, no spills at the 256-VGPR cap (2 blocks/CU from 68KB LDS).
__global__ __launch_bounds__(256, 2) void k_assign(
    const float* __restrict__ x, WS* __restrict__ ws) {
  __shared__ unsigned short ldsA[2][128][LDK];  // [hi/lo][code][k]
  __shared__ float cns[128];

  const int tid = threadIdx.x;
  const int wave = tid >> 6, lane = tid & 63;
  const int l15 = lane & 15, quad = lane >> 4;
  const int rowbase = blockIdx.x * 128 + wave * 32;

  // ---- load resident B-fragments (this wave's 32 rows, bf16 hi/lo) ----
  short8 Bhi[2][4], Blo[2][4];
#pragma unroll
  for (int Nf = 0; Nf < 2; ++Nf) {
    const float* xr = x + (size_t)(rowbase + Nf * 16 + l15) * DD;
#pragma unroll
    for (int ks = 0; ks < 4; ++ks) {
      int k0 = ks * 32 + quad * 8;
      float4 u = *(const float4*)(xr + k0);
      float4 v = *(const float4*)(xr + k0 + 4);
      float f[8] = {u.x, u.y, u.z, u.w, v.x, v.y, v.z, v.w};
      short8 bh, bl;
#pragma unroll
      for (int j = 0; j < 8; ++j) {
        unsigned short h = f2bf_rn(f[j]);
        bh[j] = (short)h;
        bl[j] = (short)f2bf_rn(f[j] - bf2f(h));
      }
      Bhi[Nf][ks] = bh; Blo[Nf][ks] = bl;
    }
  }

  // running top-2 (maximize acc), per Nf
  float rv1[2], rv2[2];
  int ri1[2], ri2[2];
#pragma unroll
  for (int Nf = 0; Nf < 2; ++Nf) { rv1[Nf] = -3.4e38f; rv2[Nf] = -3.4e38f; ri1[Nf] = 0; ri2[Nf] = 0; }

  for (int cc = 0; cc < 8; ++cc) {            // 8 chunks of 128 codes
    __syncthreads();
    // ---- stage chunk: 128 codes hi+lo -> LDS (padded), + cnorms ----
#pragma unroll
    for (int it = 0; it < 8; ++it) {
      int s = it * 256 + tid;                 // 2048 16B-segments per variant
      int row = s >> 4, seg = s & 15;
      const short8* gh = (const short8*)&ws->chi[((size_t)(cc * 128 + row)) * DD + seg * 8];
      const short8* gl = (const short8*)&ws->clo[((size_t)(cc * 128 + row)) * DD + seg * 8];
      *(short8*)&ldsA[0][row][seg * 8] = *gh;
      *(short8*)&ldsA[1][row][seg * 8] = *gl;
    }
    if (tid < 128) cns[tid] = ws->cnorm32[cc * 128 + tid];
    __syncthreads();

#pragma unroll
    for (int half = 0; half < 2; ++half) {    // 64 codes per half
      f32x4 acc[4][2];
#pragma unroll
      for (int Mf = 0; Mf < 4; ++Mf) {
        f32x4 cn4 = *(const f32x4*)&cns[half * 64 + Mf * 16 + quad * 4];
        f32x4 ini = -0.5f * cn4;
#pragma unroll
        for (int Nf = 0; Nf < 2; ++Nf) acc[Mf][Nf] = ini;
      }
#pragma unroll
      for (int ks = 0; ks < 4; ++ks) {
        short8 Ah[4], Al[4];
#pragma unroll
        for (int Mf = 0; Mf < 4; ++Mf)
          Ah[Mf] = *(const short8*)&ldsA[0][half * 64 + Mf * 16 + l15][ks * 32 + quad * 8];
#pragma unroll
        for (int Mf = 0; Mf < 4; ++Mf)
          Al[Mf] = *(const short8*)&ldsA[1][half * 64 + Mf * 16 + l15][ks * 32 + quad * 8];
#pragma unroll
        for (int Mf = 0; Mf < 4; ++Mf)
#pragma unroll
          for (int Nf = 0; Nf < 2; ++Nf)
            acc[Mf][Nf] = __builtin_amdgcn_mfma_f32_16x16x32_bf16(Ah[Mf], Bhi[Nf][ks], acc[Mf][Nf], 0, 0, 0);
#pragma unroll
        for (int Mf = 0; Mf < 4; ++Mf)
#pragma unroll
          for (int Nf = 0; Nf < 2; ++Nf)
            acc[Mf][Nf] = __builtin_amdgcn_mfma_f32_16x16x32_bf16(Ah[Mf], Blo[Nf][ks], acc[Mf][Nf], 0, 0, 0);
#pragma unroll
        for (int Mf = 0; Mf < 4; ++Mf)
#pragma unroll
          for (int Nf = 0; Nf < 2; ++Nf)
            acc[Mf][Nf] = __builtin_amdgcn_mfma_f32_16x16x32_bf16(Al[Mf], Bhi[Nf][ks], acc[Mf][Nf], 0, 0, 0);
      }
      // ---- top-2 epilogue: in-lane over 16, butterfly over quads ----
      int cb0 = cc * 128 + half * 64 + quad * 4;
#pragma unroll
      for (int Nf = 0; Nf < 2; ++Nf) {
        float v1 = -3.4e38f, v2 = -3.4e38f; int i1 = 0, i2 = 0;
#pragma unroll
        for (int Mf = 0; Mf < 4; ++Mf)
#pragma unroll
          for (int r = 0; r < 4; ++r) {
            float v = acc[Mf][Nf][r];
            int idx = cb0 + Mf * 16 + r;
            if (v > v1 || (v == v1 && idx < i1)) { v2 = v1; i2 = i1; v1 = v; i1 = idx; }
            else if (v > v2 || (v == v2 && idx < i2)) { v2 = v; i2 = idx; }
          }
#pragma unroll
        for (int st = 16; st <= 32; st <<= 1) {
          float ov1 = __shfl_xor(v1, st), ov2 = __shfl_xor(v2, st);
          int oi1 = __shfl_xor(i1, st), oi2 = __shfl_xor(i2, st);
          if (ov1 > v1 || (ov1 == v1 && oi1 < i1)) { v2 = v1; i2 = i1; v1 = ov1; i1 = oi1; }
          else if (ov1 > v2 || (ov1 == v2 && oi1 < i2)) { v2 = ov1; i2 = oi1; }
          if (ov2 > v2 || (ov2 == v2 && oi2 < i2)) { v2 = ov2; i2 = oi2; }
        }
        if (v1 > rv1[Nf] || (v1 == rv1[Nf] && i1 < ri1[Nf])) {
          if (rv1[Nf] > v2 || (rv1[Nf] == v2 && ri1[Nf] < i2)) { v2 = rv1[Nf]; i2 = ri1[Nf]; }
          rv2[Nf] = v2; ri2[Nf] = i2; rv1[Nf] = v1; ri1[Nf] = i1;
        } else {
          if (v1 > rv2[Nf] || (v1 == rv2[Nf] && i1 < ri2[Nf])) { rv2[Nf] = v1; ri2[Nf] = i1; }
        }
      }
    }
  }

  // key = -2*acc; key gap = 2*acc gap. Flag if acc gap < 7.5e-6.
  const float ACC_MARGIN = 7.5e-6f;
#pragma unroll
  for (int Nf = 0; Nf < 2; ++Nf) {
    if (quad == 0) {
      int row = rowbase + Nf * 16 + l15;
      if ((rv1[Nf] - rv2[Nf]) < ACC_MARGIN) {
        unsigned slot = atomicAdd(&ws->wl_count, 1u);
        ws->wl[slot] = (unsigned)row;
      } else {
        ws->rowidx[row] = (unsigned)ri1[Nf];
        atomicAdd(&ws->counts[ri1[Nf]], 1u);
      }
    }
  }
}

// fp64 exact argmin for flagged rows; one wave per row.
__global__ __launch_bounds__(256) void k_refine(
    const float* __restrict__ x, const float* __restrict__ cb,
    WS* __restrict__ ws) {
  unsigned count = ws->wl_count;
  int gwave = (blockIdx.x * 256 + (int)threadIdx.x) >> 6;
  int lane = threadIdx.x & 63;
  int nwaves = gridDim.x * 4;
  for (unsigned w = gwave; w < count; w += nwaves) {
    int row = (int)ws->wl[w];
    const float* xr = x + (size_t)row * DD;
    double bkey = 1e300; int bidx = 0;
    for (int m = 0; m < 16; ++m) {
      int k = lane * 16 + m;
      const float* cr = cb + (size_t)k * DD;
      double acc = 0.0;
      for (int j = 0; j < DD; ++j)
        acc = fma((double)xr[j], (double)cr[j], acc);
      double key = fma(-2.0, acc, ws->cnorm64[k]);
      if (key < bkey) { bkey = key; bidx = k; }
    }
    for (int off = 32; off; off >>= 1) {
      double ok = __shfl_xor(bkey, off);
      int oi = __shfl_xor(bidx, off);
      if (ok < bkey || (ok == bkey && oi < bidx)) { bkey = ok; bidx = oi; }
    }
    if (lane == 0) {
      ws->rowidx[row] = (unsigned)bidx;
      atomicAdd(&ws->counts[bidx], 1u);
    }
  }
}

// z_st + loss for all rows: grid-stride over float4 segments, no atomics.
__global__ __launch_bounds__(256) void k_gather(
    const float* __restrict__ x, const float* __restrict__ cb,
    float* __restrict__ out, WS* __restrict__ ws) {
  const int NSEG = NROWS * 32;
  float s = 0.0f;
  for (int g = blockIdx.x * 256 + threadIdx.x; g < NSEG; g += GATHER_BLOCKS * 256) {
    int row = g >> 5, seg = g & 31;
    unsigned idx = ws->rowidx[row];
    float4 c4 = *(const float4*)(cb + (size_t)idx * DD + seg * 4);
    float4 x4 = *(const float4*)(x + (size_t)row * DD + seg * 4);
    float d0 = c4.x - x4.x, d1 = c4.y - x4.y, d2 = c4.z - x4.z, d3 = c4.w - x4.w;
    float4 o4;
    o4.x = x4.x + d0; o4.y = x4.y + d1; o4.z = x4.z + d2; o4.w = x4.w + d3;
    *(float4*)(out + (size_t)row * DD + seg * 4) = o4;
    s += fmaf(d0, d0, fmaf(d1, d1, fmaf(d2, d2, d3 * d3)));
  }
  for (int off = 32; off; off >>= 1) s += __shfl_down(s, off);
  __shared__ float wsum[4];
  if ((threadIdx.x & 63) == 0) wsum[threadIdx.x >> 6] = s;
  __syncthreads();
  if (threadIdx.x == 0) {
    double t = (double)wsum[0] + (double)wsum[1] + (double)wsum[2] + (double)wsum[3];
    ws->lossPart[blockIdx.x] = t;
  }
}

__global__ __launch_bounds__(256) void k_final(float* __restrict__ out,
                                               WS* __restrict__ ws) {
  __shared__ double hs[256], ls[256];
  double h = 0.0;
  for (int i = threadIdx.x; i < KC; i += 256) {
    double p = (double)ws->counts[i] / (double)NROWS;
    h += p * log(p + 1e-10);
  }
  double lp = 0.0;
  for (int i = threadIdx.x; i < GATHER_BLOCKS; i += 256) lp += ws->lossPart[i];
  hs[threadIdx.x] = h;
  ls[threadIdx.x] = lp;
  __syncthreads();
  for (int off = 128; off; off >>= 1) {
    if ((int)threadIdx.x < off) {
      hs[threadIdx.x] += hs[threadIdx.x + off];
      ls[threadIdx.x] += ls[threadIdx.x + off];
    }
    __syncthreads();
  }
  if (threadIdx.x == 0) {
    double loss = ls[0] / (double)((size_t)NROWS * DD);
    out[16777216] = (float)loss;
    out[16777217] = (float)loss;
    out[16777218] = (float)exp(-hs[0]);
  }
}

extern "C" void kernel_launch(void* const* d_in, const int* in_sizes, int n_in,
                              void* d_out, int out_size, void* d_ws, size_t ws_size,
                              hipStream_t stream) {
  const float* x = (const float*)d_in[0];
  const float* cb = (const float*)d_in[1];
  float* out = (float*)d_out;
  WS* ws = (WS*)d_ws;

  hipMemsetAsync(d_ws, 0, offsetof(WS, cnorm32), stream);
  k_cvt<<<128, 256, 0, stream>>>(cb, ws);
  k_cnorm<<<KC / 256, 256, 0, stream>>>(cb, ws);
  k_assign<<<NROWS / 128, 256, 0, stream>>>(x, ws);
  k_refine<<<128, 256, 0, stream>>>(x, cb, ws);
  k_gather<<<GATHER_BLOCKS, 256, 0, stream>>>(x, cb, out, ws);
  k_final<<<1, 256, 0, stream>>>(out, ws);
}

// Round 4
// 379.701 us; speedup vs baseline: 3.6202x; 1.2473x over previous
//
#include <hip/hip_runtime.h>
#include <cstddef>
#include <math.h>

// VQ layer via bf16-split MFMA GEMM.
// S = X·C^T as 3 bf16 MFMA passes (hi*hi + hi*lo + lo*hi); argmin key
// = cnorm - 2*dot computed as argmax of acc where acc0 = -0.5*cnorm.
// Per-lane running top-2 on packed u32 keys (22-bit quantized value |
// 10-bit inverted index); near-ties (<10 quant ulp ≈ 9.5e-6 acc-gap,
// covering the rigorous 5e-6 bf16-split worst-case error) refined in fp64.

#define NROWS 131072
#define KC 1024
#define DD 128
#define LDK 136   // 128 + 8 ushort pad -> 272B row stride
#define GATHER_BLOCKS 4096

typedef __attribute__((ext_vector_type(8))) short short8;
typedef __attribute__((ext_vector_type(4))) float f32x4;

struct WS {
  unsigned wl_count;           // zeroed by k_prep
  unsigned pad0;               // zeroed
  double lossSum;              // zeroed (unused, layout padding)
  unsigned counts[KC];         // zeroed
  float cnorm32[KC];
  double cnorm64[KC];
  double lossPart[GATHER_BLOCKS];
  unsigned rowidx[NROWS];
  unsigned wl[NROWS];
  unsigned short chi[KC * DD]; // codebook bf16 hi
  unsigned short clo[KC * DD]; // codebook bf16 lo
};

static __device__ __forceinline__ unsigned short f2bf_rn(float f) {
  unsigned u = __float_as_uint(f);
  unsigned r = (u + 0x7FFFu + ((u >> 16) & 1u)) >> 16;  // RN-even
  return (unsigned short)r;
}
static __device__ __forceinline__ float bf2f(unsigned short h) {
  return __uint_as_float(((unsigned)h) << 16);
}

// prep: zero header, bf16-split codebook, fp64 cnorms. One launch.
__global__ __launch_bounds__(256) void k_prep(const float* __restrict__ cb,
                                              WS* __restrict__ ws) {
  int gid = blockIdx.x * 256 + threadIdx.x;   // 32768 threads
  if (gid < 1028) ((unsigned*)ws)[gid] = 0u;  // wl_count..counts[] = 1028 dwords
  int e0 = gid * 4;
  float4 c4 = *(const float4*)(cb + e0);
  float cf[4] = {c4.x, c4.y, c4.z, c4.w};
#pragma unroll
  for (int j = 0; j < 4; ++j) {
    unsigned short h = f2bf_rn(cf[j]);
    ws->chi[e0 + j] = h;
    ws->clo[e0 + j] = f2bf_rn(cf[j] - bf2f(h));
  }
  if (gid < KC) {
    const float* cr = cb + (size_t)gid * DD;
    double s = 0.0;
    for (int j = 0; j < DD; ++j) { double v = (double)cr[j]; s = fma(v, v, s); }
    ws->cnorm64[gid] = s;
    ws->cnorm32[gid] = (float)s;
  }
}

// block = 4 waves; each wave owns 32 x-rows (bf16 hi/lo frags resident, 64
// VGPRs); codes stream through LDS in chunks of 128, reg-pipelined one
// chunk ahead so the pre-barrier vmcnt drain overlaps compute.
__global__ __launch_bounds__(256, 2) void k_assign(
    const float* __restrict__ x, WS* __restrict__ ws) {
  __shared__ __align__(16) unsigned short ldsA[2][128][LDK];  // [hi/lo][code][k]
  __shared__ float cnsAll[KC];

  const int tid = threadIdx.x;
  const int wave = tid >> 6, lane = tid & 63;
  const int l15 = lane & 15, quad = lane >> 4;
  const int rowbase = blockIdx.x * 128 + wave * 32;

  for (int i = tid; i < KC; i += 256) cnsAll[i] = ws->cnorm32[i];

  // ---- resident B-fragments (this wave's 32 rows, bf16 hi/lo) ----
  short8 Bhi[2][4], Blo[2][4];
#pragma unroll
  for (int Nf = 0; Nf < 2; ++Nf) {
    const float* xr = x + (size_t)(rowbase + Nf * 16 + l15) * DD;
#pragma unroll
    for (int ks = 0; ks < 4; ++ks) {
      int k0 = ks * 32 + quad * 8;
      float4 u = *(const float4*)(xr + k0);
      float4 v = *(const float4*)(xr + k0 + 4);
      float f[8] = {u.x, u.y, u.z, u.w, v.x, v.y, v.z, v.w};
      short8 bh, bl;
#pragma unroll
      for (int j = 0; j < 8; ++j) {
        unsigned short h = f2bf_rn(f[j]);
        bh[j] = (short)h;
        bl[j] = (short)f2bf_rn(f[j] - bf2f(h));
      }
      Bhi[Nf][ks] = bh; Blo[Nf][ks] = bl;
    }
  }

  unsigned k1[2] = {0u, 0u}, k2[2] = {0u, 0u};
  const unsigned invq = 1023u - (unsigned)(quad * 4);

  const int srow0 = tid >> 4, sseg = tid & 15;
  short8 stg[16];
  auto issue = [&](int cc) {
#pragma unroll
    for (int it = 0; it < 8; ++it) {
      size_t g = ((size_t)(cc * 128 + it * 16 + srow0)) * DD + sseg * 8;
      stg[it * 2]     = *(const short8*)&ws->chi[g];
      stg[it * 2 + 1] = *(const short8*)&ws->clo[g];
    }
  };
  issue(0);

  for (int cc = 0; cc < 8; ++cc) {
    __syncthreads();                          // prev compute done; LDS free
#pragma unroll
    for (int it = 0; it < 8; ++it) {
      *(short8*)&ldsA[0][it * 16 + srow0][sseg * 8] = stg[it * 2];
      *(short8*)&ldsA[1][it * 16 + srow0][sseg * 8] = stg[it * 2 + 1];
    }
    __syncthreads();
    if (cc < 7) issue(cc + 1);                // prefetch next chunk into regs

#pragma unroll
    for (int half = 0; half < 2; ++half) {
      f32x4 acc[4][2];
#pragma unroll
      for (int Mf = 0; Mf < 4; ++Mf) {
        f32x4 cn4 = *(const f32x4*)&cnsAll[cc * 128 + half * 64 + Mf * 16 + quad * 4];
        f32x4 ini = -0.5f * cn4;
        acc[Mf][0] = ini; acc[Mf][1] = ini;
      }
#pragma unroll
      for (int ks = 0; ks < 4; ++ks) {
        short8 Ah[4], Al[4];
#pragma unroll
        for (int Mf = 0; Mf < 4; ++Mf) {
          Ah[Mf] = *(const short8*)&ldsA[0][half * 64 + Mf * 16 + l15][ks * 32 + quad * 8];
          Al[Mf] = *(const short8*)&ldsA[1][half * 64 + Mf * 16 + l15][ks * 32 + quad * 8];
        }
#pragma unroll
        for (int Mf = 0; Mf < 4; ++Mf)
#pragma unroll
          for (int Nf = 0; Nf < 2; ++Nf)
            acc[Mf][Nf] = __builtin_amdgcn_mfma_f32_16x16x32_bf16(Ah[Mf], Bhi[Nf][ks], acc[Mf][Nf], 0, 0, 0);
#pragma unroll
        for (int Mf = 0; Mf < 4; ++Mf)
#pragma unroll
          for (int Nf = 0; Nf < 2; ++Nf)
            acc[Mf][Nf] = __builtin_amdgcn_mfma_f32_16x16x32_bf16(Ah[Mf], Blo[Nf][ks], acc[Mf][Nf], 0, 0, 0);
#pragma unroll
        for (int Mf = 0; Mf < 4; ++Mf)
#pragma unroll
          for (int Nf = 0; Nf < 2; ++Nf)
            acc[Mf][Nf] = __builtin_amdgcn_mfma_f32_16x16x32_bf16(Al[Mf], Bhi[Nf][ks], acc[Mf][Nf], 0, 0, 0);
      }
      // ---- branch-free packed-key top-2, no shuffles ----
      // q = (acc + 2) * 2^20  (22 bits; |acc| <= 0.25 by Cauchy-Schwarz)
      int slotbase = cc * 128 + half * 64;
#pragma unroll
      for (int Nf = 0; Nf < 2; ++Nf)
#pragma unroll
        for (int Mf = 0; Mf < 4; ++Mf)
#pragma unroll
          for (int r = 0; r < 4; ++r) {
            float qf = fmaf(acc[Mf][Nf][r], 1048576.0f, 2097152.0f);
            qf = fminf(qf, 4194303.0f);       // overflow insurance
            unsigned q = (unsigned)qf;
            unsigned pk = (q << 10) + invq - (unsigned)(slotbase + Mf * 16 + r);
            unsigned lo = min(k1[Nf], pk);
            k1[Nf] = max(k1[Nf], pk);
            k2[Nf] = max(k2[Nf], lo);
          }
    }
  }

  // final cross-quad top-2 merge (only shuffles in the kernel) + write
#pragma unroll
  for (int Nf = 0; Nf < 2; ++Nf) {
    unsigned a1 = k1[Nf], a2 = k2[Nf];
#pragma unroll
    for (int st = 16; st <= 32; st <<= 1) {
      unsigned o1 = (unsigned)__shfl_xor((int)a1, st);
      unsigned o2 = (unsigned)__shfl_xor((int)a2, st);
      unsigned lo = min(a1, o1);
      a1 = max(a1, o1);
      a2 = max(lo, max(a2, o2));
    }
    if (quad == 0) {
      int row = rowbase + Nf * 16 + l15;
      unsigned gap = (a1 >> 10) - (a2 >> 10);
      int idx = 1023 - (int)(a1 & 1023u);
      if (gap < 10u) {                        // < 10 ulp = 9.5e-6 acc-gap
        unsigned slot = atomicAdd(&ws->wl_count, 1u);
        ws->wl[slot] = (unsigned)row;
      } else {
        ws->rowidx[row] = (unsigned)idx;
        atomicAdd(&ws->counts[idx], 1u);
      }
    }
  }
}

// fp64 exact argmin for flagged rows; one wave per row.
__global__ __launch_bounds__(256) void k_refine(
    const float* __restrict__ x, const float* __restrict__ cb,
    WS* __restrict__ ws) {
  unsigned count = ws->wl_count;
  int gwave = (blockIdx.x * 256 + (int)threadIdx.x) >> 6;
  int lane = threadIdx.x & 63;
  int nwaves = gridDim.x * 4;
  for (unsigned w = gwave; w < count; w += nwaves) {
    int row = (int)ws->wl[w];
    const float* xr = x + (size_t)row * DD;
    double bkey = 1e300; int bidx = 0;
    for (int m = 0; m < 16; ++m) {
      int k = lane * 16 + m;
      const float* cr = cb + (size_t)k * DD;
      double acc = 0.0;
      for (int j = 0; j < DD; ++j)
        acc = fma((double)xr[j], (double)cr[j], acc);
      double key = fma(-2.0, acc, ws->cnorm64[k]);
      if (key < bkey) { bkey = key; bidx = k; }
    }
    for (int off = 32; off; off >>= 1) {
      double ok = __shfl_xor(bkey, off);
      int oi = __shfl_xor(bidx, off);
      if (ok < bkey || (ok == bkey && oi < bidx)) { bkey = ok; bidx = oi; }
    }
    if (lane == 0) {
      ws->rowidx[row] = (unsigned)bidx;
      atomicAdd(&ws->counts[bidx], 1u);
    }
  }
}

// z_st + loss for all rows: grid-stride over float4 segments, no atomics.
__global__ __launch_bounds__(256) void k_gather(
    const float* __restrict__ x, const float* __restrict__ cb,
    float* __restrict__ out, WS* __restrict__ ws) {
  const int NSEG = NROWS * 32;
  float s = 0.0f;
  for (int g = blockIdx.x * 256 + threadIdx.x; g < NSEG; g += GATHER_BLOCKS * 256) {
    int row = g >> 5, seg = g & 31;
    unsigned idx = ws->rowidx[row];
    float4 c4 = *(const float4*)(cb + (size_t)idx * DD + seg * 4);
    float4 x4 = *(const float4*)(x + (size_t)row * DD + seg * 4);
    float d0 = c4.x - x4.x, d1 = c4.y - x4.y, d2 = c4.z - x4.z, d3 = c4.w - x4.w;
    float4 o4;
    o4.x = x4.x + d0; o4.y = x4.y + d1; o4.z = x4.z + d2; o4.w = x4.w + d3;
    *(float4*)(out + (size_t)row * DD + seg * 4) = o4;
    s += fmaf(d0, d0, fmaf(d1, d1, fmaf(d2, d2, d3 * d3)));
  }
  for (int off = 32; off; off >>= 1) s += __shfl_down(s, off);
  __shared__ float wsum[4];
  if ((threadIdx.x & 63) == 0) wsum[threadIdx.x >> 6] = s;
  __syncthreads();
  if (threadIdx.x == 0) {
    double t = (double)wsum[0] + (double)wsum[1] + (double)wsum[2] + (double)wsum[3];
    ws->lossPart[blockIdx.x] = t;
  }
}

__global__ __launch_bounds__(256) void k_final(float* __restrict__ out,
                                               WS* __restrict__ ws) {
  __shared__ double hs[256], ls[256];
  double h = 0.0;
  for (int i = threadIdx.x; i < KC; i += 256) {
    double p = (double)ws->counts[i] / (double)NROWS;
    h += p * log(p + 1e-10);
  }
  double lp = 0.0;
  for (int i = threadIdx.x; i < GATHER_BLOCKS; i += 256) lp += ws->lossPart[i];
  hs[threadIdx.x] = h;
  ls[threadIdx.x] = lp;
  __syncthreads();
  for (int off = 128; off; off >>= 1) {
    if ((int)threadIdx.x < off) {
      hs[threadIdx.x] += hs[threadIdx.x + off];
      ls[threadIdx.x] += ls[threadIdx.x + off];
    }
    __syncthreads();
  }
  if (threadIdx.x == 0) {
    double loss = ls[0] / (double)((size_t)NROWS * DD);
    out[16777216] = (float)loss;
    out[16777217] = (float)loss;
    out[16777218] = (float)exp(-hs[0]);
  }
}

extern "C" void kernel_launch(void* const* d_in, const int* in_sizes, int n_in,
                              void* d_out, int out_size, void* d_ws, size_t ws_size,
                              hipStream_t stream) {
  const float* x = (const float*)d_in[0];
  const float* cb = (const float*)d_in[1];
  float* out = (float*)d_out;
  WS* ws = (WS*)d_ws;

  k_prep<<<128, 256, 0, stream>>>(cb, ws);
  k_assign<<<NROWS / 128, 256, 0, stream>>>(x, ws);
  k_refine<<<128, 256, 0, stream>>>(x, cb, ws);
  k_gather<<<GATHER_BLOCKS, 256, 0, stream>>>(x, cb, out, ws);
  k_final<<<1, 256, 0, stream>>>(out, ws);
}

// Round 5
// 323.850 us; speedup vs baseline: 4.2445x; 1.1725x over previous
//
#include <hip/hip_runtime.h>
#include <cstddef>
#include <math.h>

// VQ layer via bf16-split MFMA GEMM.
// S = X·C^T as 3 bf16 MFMA passes (hi*hi + hi*lo + lo*hi); argmin key
// = cnorm - 2*dot computed as argmax of acc where acc0 = -0.5*cnorm.
// Codebook stored bf16-split in global, XOR-swizzled at granule level so
// global_load_lds (wave-uniform dest, no padding possible) yields a
// bank-balanced LDS layout. Per-lane running top-2 on packed u32 keys;
// near-ties (<10 quant ulp ≈ 9.5e-6 acc-gap) refined in fp64.

#define NROWS 131072
#define KC 1024
#define DD 128
#define GATHER_BLOCKS 4096

typedef __attribute__((ext_vector_type(8))) short short8;
typedef __attribute__((ext_vector_type(4))) float f32x4;
typedef __attribute__((ext_vector_type(4))) unsigned short u16x4;

struct WS {
  unsigned wl_count;           // zeroed by k_prep
  unsigned pad0;               // zeroed
  double lossSum;              // zeroed (unused, layout padding)
  unsigned counts[KC];         // zeroed
  float cnorm32[KC];
  double cnorm64[KC];
  double lossPart[GATHER_BLOCKS];
  unsigned rowidx[NROWS];
  unsigned wl[NROWS];
  unsigned short chi[KC * DD]; // codebook bf16 hi (granule-swizzled)
  unsigned short clo[KC * DD]; // codebook bf16 lo (granule-swizzled)
};

static __device__ __forceinline__ unsigned short f2bf_rn(float f) {
  unsigned u = __float_as_uint(f);
  unsigned r = (u + 0x7FFFu + ((u >> 16) & 1u)) >> 16;  // RN-even
  return (unsigned short)r;
}
static __device__ __forceinline__ float bf2f(unsigned short h) {
  return __uint_as_float(((unsigned)h) << 16);
}

// prep: zero header, bf16-split + granule-swizzle codebook, fp64 cnorms.
__global__ __launch_bounds__(256) void k_prep(const float* __restrict__ cb,
                                              WS* __restrict__ ws) {
  int gid = blockIdx.x * 256 + threadIdx.x;   // 32768 threads
  if (gid < 1028) ((unsigned*)ws)[gid] = 0u;  // wl_count..counts[]
  int e0 = gid * 4;
  int code = e0 >> 7, k = e0 & 127;
  int g = k >> 3, j0 = k & 7;                 // granule, 16B-aligned sub
  int gs = g ^ (code & 7);                    // swizzled granule
  int dst = code * DD + gs * 8 + j0;
  float4 c4 = *(const float4*)(cb + e0);
  float cf[4] = {c4.x, c4.y, c4.z, c4.w};
  u16x4 hv, lv;
#pragma unroll
  for (int j = 0; j < 4; ++j) {
    unsigned short h = f2bf_rn(cf[j]);
    hv[j] = h;
    lv[j] = f2bf_rn(cf[j] - bf2f(h));
  }
  *(u16x4*)&ws->chi[dst] = hv;
  *(u16x4*)&ws->clo[dst] = lv;
  if (gid < KC) {
    const float* cr = cb + (size_t)gid * DD;
    double a0 = 0, a1 = 0, a2 = 0, a3 = 0;
    for (int j = 0; j < DD; j += 4) {
      float4 v = *(const float4*)(cr + j);
      a0 = fma((double)v.x, (double)v.x, a0);
      a1 = fma((double)v.y, (double)v.y, a1);
      a2 = fma((double)v.z, (double)v.z, a2);
      a3 = fma((double)v.w, (double)v.w, a3);
    }
    double s = (a0 + a1) + (a2 + a3);
    ws->cnorm64[gid] = s;
    ws->cnorm32[gid] = (float)s;
  }
}

// block = 4 waves; each wave owns 64 x-rows (bf16 hi/lo frags resident, 128
// VGPRs); codes stream through LDS in chunks of 128 via global_load_lds.
__global__ __launch_bounds__(256, 2) void k_assign(
    const float* __restrict__ x, WS* __restrict__ ws) {
  __shared__ __align__(16) unsigned short ldsC[2][128][128];  // [hi/lo][code][k-swz]
  __shared__ float cnsAll[KC];

  const int tid = threadIdx.x;
  const int wave = tid >> 6, lane = tid & 63;
  const int l15 = lane & 15, quad = lane >> 4;
  const int rowbase = blockIdx.x * 256 + wave * 64;

  for (int i = tid; i < KC; i += 256) cnsAll[i] = ws->cnorm32[i];

  // ---- resident B-fragments (this wave's 64 rows, bf16 hi/lo) ----
  short8 Bhi[4][4], Blo[4][4];
#pragma unroll
  for (int Nf = 0; Nf < 4; ++Nf) {
    const float* xr = x + (size_t)(rowbase + Nf * 16 + l15) * DD;
#pragma unroll
    for (int ks = 0; ks < 4; ++ks) {
      int k0 = ks * 32 + quad * 8;
      float4 u = *(const float4*)(xr + k0);
      float4 v = *(const float4*)(xr + k0 + 4);
      float f[8] = {u.x, u.y, u.z, u.w, v.x, v.y, v.z, v.w};
      short8 bh, bl;
#pragma unroll
      for (int j = 0; j < 8; ++j) {
        unsigned short h = f2bf_rn(f[j]);
        bh[j] = (short)h;
        bl[j] = (short)f2bf_rn(f[j] - bf2f(h));
      }
      Bhi[Nf][ks] = bh; Blo[Nf][ks] = bl;
    }
  }

  unsigned k1[4] = {0u, 0u, 0u, 0u}, k2[4] = {0u, 0u, 0u, 0u};
  const unsigned invq = 1023u - (unsigned)(quad * 4);
  const int swz = l15 & 7;                    // read-side granule XOR
  const unsigned short* gsrc = (wave < 2) ? ws->chi : ws->clo;
  const int carr = wave >> 1;                 // which LDS array this wave fills
  const int c0 = (wave & 1) * 64;             // 64 codes per wave per chunk

  for (int cc = 0; cc < 8; ++cc) {
    __syncthreads();                          // prev compute done; LDS free
    // ---- stage chunk via async DMA: 16 x 1KB per wave ----
#pragma unroll
    for (int i = 0; i < 16; ++i) {
      const unsigned short* gp =
          gsrc + ((size_t)(cc * 128 + c0 + i * 4)) * DD + lane * 8;
      __builtin_amdgcn_global_load_lds(
          (const __attribute__((address_space(1))) unsigned int*)gp,
          (__attribute__((address_space(3))) unsigned int*)&ldsC[carr][c0 + i * 4][0],
          16, 0, 0);
    }
    __syncthreads();                          // barrier drains vmcnt -> LDS valid

#pragma unroll
    for (int half = 0; half < 2; ++half) {
      f32x4 acc[4][4];
#pragma unroll
      for (int Mf = 0; Mf < 4; ++Mf) {
        f32x4 cn4 = *(const f32x4*)&cnsAll[cc * 128 + half * 64 + Mf * 16 + quad * 4];
        f32x4 ini = -0.5f * cn4;
#pragma unroll
        for (int Nf = 0; Nf < 4; ++Nf) acc[Mf][Nf] = ini;
      }
#pragma unroll
      for (int ks = 0; ks < 4; ++ks) {
        const int goff = (((ks * 4 + quad) ^ swz) * 8);   // swizzled k-offset (ushorts)
        short8 Ah[4], Al[4];
#pragma unroll
        for (int Mf = 0; Mf < 4; ++Mf) {
          const int r = half * 64 + Mf * 16 + l15;
          Ah[Mf] = *(const short8*)&ldsC[0][r][goff];
          Al[Mf] = *(const short8*)&ldsC[1][r][goff];
        }
#pragma unroll
        for (int Mf = 0; Mf < 4; ++Mf)
#pragma unroll
          for (int Nf = 0; Nf < 4; ++Nf)
            acc[Mf][Nf] = __builtin_amdgcn_mfma_f32_16x16x32_bf16(Ah[Mf], Bhi[Nf][ks], acc[Mf][Nf], 0, 0, 0);
#pragma unroll
        for (int Mf = 0; Mf < 4; ++Mf)
#pragma unroll
          for (int Nf = 0; Nf < 4; ++Nf)
            acc[Mf][Nf] = __builtin_amdgcn_mfma_f32_16x16x32_bf16(Ah[Mf], Blo[Nf][ks], acc[Mf][Nf], 0, 0, 0);
#pragma unroll
        for (int Mf = 0; Mf < 4; ++Mf)
#pragma unroll
          for (int Nf = 0; Nf < 4; ++Nf)
            acc[Mf][Nf] = __builtin_amdgcn_mfma_f32_16x16x32_bf16(Al[Mf], Bhi[Nf][ks], acc[Mf][Nf], 0, 0, 0);
      }
      // ---- branch-free packed-key top-2 ----
      int slotbase = cc * 128 + half * 64;
#pragma unroll
      for (int Nf = 0; Nf < 4; ++Nf)
#pragma unroll
        for (int Mf = 0; Mf < 4; ++Mf)
#pragma unroll
          for (int r = 0; r < 4; ++r) {
            float qf = fmaf(acc[Mf][Nf][r], 1048576.0f, 2097152.0f);
            qf = fminf(qf, 4194303.0f);
            unsigned q = (unsigned)qf;
            unsigned pk = (q << 10) + invq - (unsigned)(slotbase + Mf * 16 + r);
            unsigned lo = min(k1[Nf], pk);
            k1[Nf] = max(k1[Nf], pk);
            k2[Nf] = max(k2[Nf], lo);
          }
    }
  }

  // final cross-quad top-2 merge + write
#pragma unroll
  for (int Nf = 0; Nf < 4; ++Nf) {
    unsigned a1 = k1[Nf], a2 = k2[Nf];
#pragma unroll
    for (int st = 16; st <= 32; st <<= 1) {
      unsigned o1 = (unsigned)__shfl_xor((int)a1, st);
      unsigned o2 = (unsigned)__shfl_xor((int)a2, st);
      unsigned lo = min(a1, o1);
      a1 = max(a1, o1);
      a2 = max(lo, max(a2, o2));
    }
    if (quad == 0) {
      int row = rowbase + Nf * 16 + l15;
      unsigned gap = (a1 >> 10) - (a2 >> 10);
      int idx = 1023 - (int)(a1 & 1023u);
      if (gap < 10u) {
        unsigned slot = atomicAdd(&ws->wl_count, 1u);
        ws->wl[slot] = (unsigned)row;
      } else {
        ws->rowidx[row] = (unsigned)idx;
        atomicAdd(&ws->counts[idx], 1u);
      }
    }
  }
}

// fp64 exact argmin for flagged rows; one wave per row, 4 indep fp64 chains.
__global__ __launch_bounds__(256) void k_refine(
    const float* __restrict__ x, const float* __restrict__ cb,
    WS* __restrict__ ws) {
  unsigned count = ws->wl_count;
  int gwave = (blockIdx.x * 256 + (int)threadIdx.x) >> 6;
  int lane = threadIdx.x & 63;
  int nwaves = gridDim.x * 4;
  for (unsigned w = gwave; w < count; w += nwaves) {
    int row = (int)ws->wl[w];
    const float* xr = x + (size_t)row * DD;
    double bkey = 1e300; int bidx = 0;
    for (int m = 0; m < 16; ++m) {
      int k = lane * 16 + m;
      const float* cr = cb + (size_t)k * DD;
      double a0 = 0, a1 = 0, a2 = 0, a3 = 0;
      for (int j = 0; j < DD; j += 4) {
        float4 xv = *(const float4*)(xr + j);
        float4 cv = *(const float4*)(cr + j);
        a0 = fma((double)xv.x, (double)cv.x, a0);
        a1 = fma((double)xv.y, (double)cv.y, a1);
        a2 = fma((double)xv.z, (double)cv.z, a2);
        a3 = fma((double)xv.w, (double)cv.w, a3);
      }
      double key = fma(-2.0, (a0 + a1) + (a2 + a3), ws->cnorm64[k]);
      if (key < bkey) { bkey = key; bidx = k; }
    }
    for (int off = 32; off; off >>= 1) {
      double ok = __shfl_xor(bkey, off);
      int oi = __shfl_xor(bidx, off);
      if (ok < bkey || (ok == bkey && oi < bidx)) { bkey = ok; bidx = oi; }
    }
    if (lane == 0) {
      ws->rowidx[row] = (unsigned)bidx;
      atomicAdd(&ws->counts[bidx], 1u);
    }
  }
}

// z_st + loss for all rows: grid-stride over float4 segments, no atomics.
__global__ __launch_bounds__(256) void k_gather(
    const float* __restrict__ x, const float* __restrict__ cb,
    float* __restrict__ out, WS* __restrict__ ws) {
  const int NSEG = NROWS * 32;
  float s = 0.0f;
  for (int g = blockIdx.x * 256 + threadIdx.x; g < NSEG; g += GATHER_BLOCKS * 256) {
    int row = g >> 5, seg = g & 31;
    unsigned idx = ws->rowidx[row];
    float4 c4 = *(const float4*)(cb + (size_t)idx * DD + seg * 4);
    float4 x4 = *(const float4*)(x + (size_t)row * DD + seg * 4);
    float d0 = c4.x - x4.x, d1 = c4.y - x4.y, d2 = c4.z - x4.z, d3 = c4.w - x4.w;
    float4 o4;
    o4.x = x4.x + d0; o4.y = x4.y + d1; o4.z = x4.z + d2; o4.w = x4.w + d3;
    *(float4*)(out + (size_t)row * DD + seg * 4) = o4;
    s += fmaf(d0, d0, fmaf(d1, d1, fmaf(d2, d2, d3 * d3)));
  }
  for (int off = 32; off; off >>= 1) s += __shfl_down(s, off);
  __shared__ float wsum[4];
  if ((threadIdx.x & 63) == 0) wsum[threadIdx.x >> 6] = s;
  __syncthreads();
  if (threadIdx.x == 0) {
    double t = (double)wsum[0] + (double)wsum[1] + (double)wsum[2] + (double)wsum[3];
    ws->lossPart[blockIdx.x] = t;
  }
}

__global__ __launch_bounds__(256) void k_final(float* __restrict__ out,
                                               WS* __restrict__ ws) {
  __shared__ double hs[256], ls[256];
  double h = 0.0;
  for (int i = threadIdx.x; i < KC; i += 256) {
    double p = (double)ws->counts[i] / (double)NROWS;
    h += p * log(p + 1e-10);
  }
  double lp = 0.0;
  for (int i = threadIdx.x; i < GATHER_BLOCKS; i += 256) lp += ws->lossPart[i];
  hs[threadIdx.x] = h;
  ls[threadIdx.x] = lp;
  __syncthreads();
  for (int off = 128; off; off >>= 1) {
    if ((int)threadIdx.x < off) {
      hs[threadIdx.x] += hs[threadIdx.x + off];
      ls[threadIdx.x] += ls[threadIdx.x + off];
    }
    __syncthreads();
  }
  if (threadIdx.x == 0) {
    double loss = ls[0] / (double)((size_t)NROWS * DD);
    out[16777216] = (float)loss;
    out[16777217] = (float)loss;
    out[16777218] = (float)exp(-hs[0]);
  }
}

extern "C" void kernel_launch(void* const* d_in, const int* in_sizes, int n_in,
                              void* d_out, int out_size, void* d_ws, size_t ws_size,
                              hipStream_t stream) {
  const float* x = (const float*)d_in[0];
  const float* cb = (const float*)d_in[1];
  float* out = (float*)d_out;
  WS* ws = (WS*)d_ws;

  k_prep<<<128, 256, 0, stream>>>(cb, ws);
  k_assign<<<NROWS / 256, 256, 0, stream>>>(x, ws);
  k_refine<<<2048, 256, 0, stream>>>(x, cb, ws);
  k_gather<<<GATHER_BLOCKS, 256, 0, stream>>>(x, cb, out, ws);
  k_final<<<1, 256, 0, stream>>>(out, ws);
}